// Round 2
// baseline (21.312 us; speedup 1.0000x reference)
//
#include <hip/hip_runtime.h>

#define NQ 16

// Prep: ct[q] = cos(theta[q]) * w[q], ws[16] = bias. One tiny block.
__global__ void qfc_prep(const float* __restrict__ theta,
                         const float* __restrict__ w,
                         const float* __restrict__ bias,
                         float* __restrict__ ws)
{
    int q = threadIdx.x;
    if (q < NQ) ws[q] = __cosf(theta[q]) * w[q];
    if (q == NQ) ws[NQ] = bias[0];
}

// Main: 2 tokens per thread, 8 outstanding dwordx4 loads, 2 indep acc chains.
__global__ __launch_bounds__(256) void qfc_kernel(
    const float* __restrict__ x,
    const float* __restrict__ ws,
    float* __restrict__ out,
    int ntok2)   // ntok/2
{
    int t = blockIdx.x * blockDim.x + threadIdx.x;
    if (t >= ntok2) return;

    // Uniform addresses -> scalar loads (s_load), broadcast free.
    float ct[NQ];
#pragma unroll
    for (int q = 0; q < NQ; ++q) ct[q] = ws[q];
    float bias = ws[NQ];

    const float4* xv = reinterpret_cast<const float4*>(x) + (size_t)t * 8;

    // Issue all 8 loads up front for ILP.
    float4 v[8];
#pragma unroll
    for (int m = 0; m < 8; ++m) v[m] = xv[m];

    float acc0 = bias, acc1 = bias;
#pragma unroll
    for (int m = 0; m < 4; ++m) {
        acc0 += __cosf(v[m].x) * ct[4 * m + 0];
        acc0 += __cosf(v[m].y) * ct[4 * m + 1];
        acc0 += __cosf(v[m].z) * ct[4 * m + 2];
        acc0 += __cosf(v[m].w) * ct[4 * m + 3];
    }
#pragma unroll
    for (int m = 0; m < 4; ++m) {
        acc1 += __cosf(v[4 + m].x) * ct[4 * m + 0];
        acc1 += __cosf(v[4 + m].y) * ct[4 * m + 1];
        acc1 += __cosf(v[4 + m].z) * ct[4 * m + 2];
        acc1 += __cosf(v[4 + m].w) * ct[4 * m + 3];
    }

    reinterpret_cast<float2*>(out)[t] = make_float2(acc0, acc1);
}

extern "C" void kernel_launch(void* const* d_in, const int* in_sizes, int n_in,
                              void* d_out, int out_size, void* d_ws, size_t ws_size,
                              hipStream_t stream) {
    const float* x     = (const float*)d_in[0];  // [B, S, 16]
    const float* theta = (const float*)d_in[1];  // [16]
    const float* w     = (const float*)d_in[2];  // [1, 16]
    const float* bias  = (const float*)d_in[3];  // [1]
    float* out = (float*)d_out;                  // [B*S] flat
    float* ws  = (float*)d_ws;                   // ct[16] + bias

    qfc_prep<<<1, 64, 0, stream>>>(theta, w, bias, ws);

    int ntok2 = out_size / 2;                    // 524,288 thread-pairs
    int block = 256;
    int grid = (ntok2 + block - 1) / block;      // 2048 blocks
    qfc_kernel<<<grid, block, 0, stream>>>(x, ws, out, ntok2);
}

// Round 3
// 20.918 us; speedup vs baseline: 1.0189x; 1.0189x over previous
//
#include <hip/hip_runtime.h>

#define NQ 16

// Single kernel: 4 tokens per thread. ct[] recomputed per-thread (amortized
// 4x) — avoids a second graph node, which cost +5us in R2.
__global__ __launch_bounds__(256) void qfc_kernel(
    const float* __restrict__ x,
    const float* __restrict__ theta,
    const float* __restrict__ w,
    const float* __restrict__ bias,
    float* __restrict__ out,
    int ntok4)   // ntok/4
{
    int t = blockIdx.x * blockDim.x + threadIdx.x;
    if (t >= ntok4) return;

    // theta/w/bias addresses are wave-uniform -> scalar loads; 16 v_cos + 16
    // v_mul per thread, amortized over 4 tokens.
    float ct[NQ];
#pragma unroll
    for (int q = 0; q < NQ; ++q) ct[q] = __cosf(theta[q]) * w[q];
    float bb = bias[0];

    const float4* xv = reinterpret_cast<const float4*>(x) + (size_t)t * 16;

    // 16 dwordx4 loads in flight (256 B/thread).
    float4 v[16];
#pragma unroll
    for (int m = 0; m < 16; ++m) v[m] = xv[m];

    float acc[4] = {bb, bb, bb, bb};
#pragma unroll
    for (int k = 0; k < 4; ++k) {
#pragma unroll
        for (int m = 0; m < 4; ++m) {
            const float4& u = v[4 * k + m];
            acc[k] += __cosf(u.x) * ct[4 * m + 0];
            acc[k] += __cosf(u.y) * ct[4 * m + 1];
            acc[k] += __cosf(u.z) * ct[4 * m + 2];
            acc[k] += __cosf(u.w) * ct[4 * m + 3];
        }
    }

    reinterpret_cast<float4*>(out)[t] = make_float4(acc[0], acc[1], acc[2], acc[3]);
}

extern "C" void kernel_launch(void* const* d_in, const int* in_sizes, int n_in,
                              void* d_out, int out_size, void* d_ws, size_t ws_size,
                              hipStream_t stream) {
    const float* x     = (const float*)d_in[0];  // [B, S, 16]
    const float* theta = (const float*)d_in[1];  // [16]
    const float* w     = (const float*)d_in[2];  // [1, 16]
    const float* bias  = (const float*)d_in[3];  // [1]
    float* out = (float*)d_out;                  // [B*S] flat

    int ntok4 = out_size / 4;                    // 262,144 threads
    int block = 256;
    int grid = (ntok4 + block - 1) / block;      // 1024 blocks
    qfc_kernel<<<grid, block, 0, stream>>>(x, theta, w, bias, out, ntok4);
}

// Round 4
// 16.315 us; speedup vs baseline: 1.3063x; 1.2821x over previous
//
#include <hip/hip_runtime.h>

#define NQ 16

// 2 tokens/thread (t and t+N/2), 8 dwordx4 loads in flight, ct[] forced to
// SGPRs via readfirstlane, launch_bounds pins <=64 VGPR for 8 waves/SIMD.
__global__ __launch_bounds__(256, 8) void qfc_kernel(
    const float* __restrict__ x,
    const float* __restrict__ theta,
    const float* __restrict__ w,
    const float* __restrict__ bias,
    float* __restrict__ out,
    int ntok2)   // ntok/2
{
    int t = blockIdx.x * blockDim.x + threadIdx.x;
    if (t >= ntok2) return;

    // theta/w are wave-uniform; hoist cos(theta)*w into SGPRs to save VGPRs.
    float ct[NQ];
#pragma unroll
    for (int q = 0; q < NQ; ++q) {
        float c = __cosf(theta[q]) * w[q];
        ct[q] = __int_as_float(__builtin_amdgcn_readfirstlane(__float_as_int(c)));
    }
    float bb = bias[0];

    const float4* xv = reinterpret_cast<const float4*>(x);
    size_t b0 = (size_t)t * 4;            // token t
    size_t b1 = b0 + (size_t)ntok2 * 4;   // token t + ntok2

    float4 v0[4], v1[4];
#pragma unroll
    for (int m = 0; m < 4; ++m) v0[m] = xv[b0 + m];
#pragma unroll
    for (int m = 0; m < 4; ++m) v1[m] = xv[b1 + m];

    float a0 = bb, a1 = bb;
#pragma unroll
    for (int m = 0; m < 4; ++m) {
        a0 += __cosf(v0[m].x) * ct[4 * m + 0];
        a0 += __cosf(v0[m].y) * ct[4 * m + 1];
        a0 += __cosf(v0[m].z) * ct[4 * m + 2];
        a0 += __cosf(v0[m].w) * ct[4 * m + 3];
        a1 += __cosf(v1[m].x) * ct[4 * m + 0];
        a1 += __cosf(v1[m].y) * ct[4 * m + 1];
        a1 += __cosf(v1[m].z) * ct[4 * m + 2];
        a1 += __cosf(v1[m].w) * ct[4 * m + 3];
    }

    out[t] = a0;
    out[t + ntok2] = a1;
}

extern "C" void kernel_launch(void* const* d_in, const int* in_sizes, int n_in,
                              void* d_out, int out_size, void* d_ws, size_t ws_size,
                              hipStream_t stream) {
    const float* x     = (const float*)d_in[0];  // [B, S, 16]
    const float* theta = (const float*)d_in[1];  // [16]
    const float* w     = (const float*)d_in[2];  // [1, 16]
    const float* bias  = (const float*)d_in[3];  // [1]
    float* out = (float*)d_out;                  // [B*S] flat

    int ntok2 = out_size / 2;                    // 524,288 threads
    int block = 256;
    int grid = (ntok2 + block - 1) / block;      // 2048 blocks
    qfc_kernel<<<grid, block, 0, stream>>>(x, theta, w, bias, out, ntok2);
}